// Round 19
// baseline (121.716 us; speedup 1.0000x reference)
//
#include <hip/hip_runtime.h>
#include <hip/hip_cooperative_groups.h>
#include <stdint.h>

namespace cg = cooperative_groups;

#define BB 4
#define NN 32768
#define PRE 4096
#define POST 512
#define NMS_TH 0.7f
#define MIDCAP 8192
#define KCAP 576          // max kept before early-exit: 511 + 64
#define BPB 8             // blocks per batch
#define NBLK (BB * BPB)   // 32 blocks

typedef unsigned long long u64;
typedef unsigned int u32;

__device__ __forceinline__ u32 orderable(float f) {
  u32 u = __float_as_uint(f);
  return (u & 0x80000000u) ? ~u : (u | 0x80000000u);
}
__device__ __forceinline__ float unorderable(u32 o) {
  u32 u = (o & 0x80000000u) ? (o & 0x7fffffffu) : ~o;
  return __uint_as_float(u);
}
// Monotone fixed-point bucket: uniform in score space (scores in [0,1)).
__device__ __forceinline__ u32 bucket_of(float s) {
  u32 v = (u32)(s * 2147483648.0f);
  u32 bk = v >> 20;
  return bk > 2047u ? 2047u : bk;
}
__device__ __forceinline__ u64 readlane64(u64 v, int l) {
  u32 lo = (u32)__builtin_amdgcn_readlane((int)(u32)v, l);
  u32 hi = (u32)__builtin_amdgcn_readlane((int)(u32)(v >> 32), l);
  return ((u64)hi << 32) | lo;
}
// IoU fast compare (threshold form) with margin tracking; exact-divide twin.
// Same op order as reference: denom = ((a1 + a2) - inter) + 1e-6.
__device__ __forceinline__ bool iou_fast(float4 a, float aa, float4 b, float ba, float& mm) {
  float ix = fminf(a.z, b.z) - fmaxf(a.x, b.x); ix = fmaxf(0.0f, ix);
  float iy = fminf(a.w, b.w) - fmaxf(a.y, b.y); iy = fmaxf(0.0f, iy);
  float inter = ix * iy;
  float denom = ((aa + ba) - inter) + 1e-6f;
  float t = 0.7f * denom;
  mm = fminf(mm, fabsf(inter - t) - 2e-5f * t);   // band >> max rounding skew (~4e-7)
  return inter > t;
}
__device__ __forceinline__ bool iou_exact(float4 a, float aa, float4 b, float ba) {
  float ix = fminf(a.z, b.z) - fmaxf(a.x, b.x); ix = fmaxf(0.0f, ix);
  float iy = fminf(a.w, b.w) - fmaxf(a.y, b.y); iy = fmaxf(0.0f, iy);
  float inter = ix * iy;
  float denom = ((aa + ba) - inter) + 1e-6f;
  return (inter / denom) > NMS_TH;
}

// Cooperative single-launch pipeline: 32 blocks x 1024 threads, 8 blocks/batch.
// 3 grid syncs. Select is computed REDUNDANTLY per block (no sync needed
// between select and compact). NMS checks candidates directly vs the LDS kept
// list (no mask matrix).
__global__ __launch_bounds__(1024, 1) void nms_coop_kernel(
    const float* __restrict__ boxes, const float* __restrict__ cls,
    u64* __restrict__ keysG, int* __restrict__ labelsG,
    u64* __restrict__ selG, u64* __restrict__ midG,
    float4* __restrict__ Pg, float* __restrict__ ARg,
    float* __restrict__ topBox, float* __restrict__ topS, int* __restrict__ topL,
    u32* __restrict__ gcur, u32* __restrict__ cnt_mid, u32* __restrict__ histP,
    float* __restrict__ out) {
  cg::grid_group grid = cg::this_grid();
  __shared__ u32 sfx[2048];
  __shared__ float4 keptP[KCAP];
  __shared__ float keptAR[KCAP];
  __shared__ u64 dLDS[64];
  __shared__ u64 kwLDS[64];
  __shared__ u32 supArr[64];
  __shared__ u32 Tsh, C1sh, knSh;

  int tid = threadIdx.x;
  int b = blockIdx.x >> 3, sub = blockIdx.x & 7;
  int wv = tid >> 6, lane = tid & 63;

  // ---- A: zero global counters; scores/keys/labels + per-block LDS hist ----
  {
    int zid = blockIdx.x * 1024 + tid;
    if (zid < BB * 2048) gcur[zid] = 0;
    if (zid < BB) cnt_mid[zid] = 0;
  }
  for (int t = tid; t < 2048; t += 1024) sfx[t] = 0;
  __syncthreads();
  u64* keysB = keysG + (size_t)b * NN;
  int* labsB = labelsG + (size_t)b * NN;
  const float* clsB = cls + (size_t)b * NN * 3;
  {
    int t4 = sub * 1024 + tid;                     // quad id within batch [0, 8192)
    const float4* c4 = (const float4*)(clsB + (size_t)t4 * 12);
    float4 va = c4[0], vb = c4[1], vc = c4[2];
    float v[12] = {va.x, va.y, va.z, va.w, vb.x, vb.y, vb.z, vb.w, vc.x, vc.y, vc.z, vc.w};
    u64 ks[4]; int ls[4];
#pragma unroll
    for (int p = 0; p < 4; ++p) {
      float s = v[3 * p]; int l = 0;
      if (v[3 * p + 1] > s) { s = v[3 * p + 1]; l = 1; }
      if (v[3 * p + 2] > s) { s = v[3 * p + 2]; l = 2; }
      int n = t4 * 4 + p;
      ks[p] = ((u64)orderable(s) << 32) | (u32)(~(u32)n);
      ls[p] = l;
      atomicAdd(&sfx[bucket_of(s)], 1u);
    }
    *(ulonglong2*)(keysB + t4 * 4) = make_ulonglong2(ks[0], ks[1]);
    *(ulonglong2*)(keysB + t4 * 4 + 2) = make_ulonglong2(ks[2], ks[3]);
    *(int4*)(labsB + t4 * 4) = make_int4(ls[0], ls[1], ls[2], ls[3]);
  }
  __syncthreads();
  for (int t = tid; t < 2048; t += 1024) histP[(size_t)blockIdx.x * 2048 + t] = sfx[t];
  grid.sync();                                     // ---- SYNC 1 ----

  // ---- select (REDUNDANT per block, batch-local): sum 8 partials; suffix-scan ----
  for (int t = tid; t < 2048; t += 1024) {
    u32 s = 0;
#pragma unroll
    for (int j = 0; j < BPB; ++j) s += histP[(size_t)(b * BPB + j) * 2048 + t];
    sfx[t] = s;
  }
  __syncthreads();
  for (int d = 1; d < 2048; d <<= 1) {
    int t0 = tid, t1 = tid + 1024;
    u32 v0 = (t0 + d < 2048) ? sfx[t0 + d] : 0;
    u32 v1 = (t1 + d < 2048) ? sfx[t1 + d] : 0;
    __syncthreads();
    sfx[t0] += v0; sfx[t1] += v1;
    __syncthreads();
  }
#pragma unroll
  for (int i = 0; i < 2; ++i) {
    int t = tid + i * 1024;
    u32 above = (t + 1 < 2048) ? sfx[t + 1] : 0;
    if (above < PRE && sfx[t] >= PRE) { Tsh = (u32)t; C1sh = above; }
  }
  __syncthreads();
  u32 T = Tsh, C1 = C1sh;

  // ---- B: compact (global per-bucket atomic offsets + LDS segment bases) ----
  u64* selB = selG + ((size_t)b << 12);
  u64* midB = midG + (size_t)b * MIDCAP;
  {
    int t4 = sub * 1024 + tid;
    ulonglong2 k01 = *(const ulonglong2*)(keysB + t4 * 4);
    ulonglong2 k23 = *(const ulonglong2*)(keysB + t4 * 4 + 2);
    u64 kk[4] = {k01.x, k01.y, k23.x, k23.y};
#pragma unroll
    for (int p = 0; p < 4; ++p) {
      u64 key = kk[p];
      u32 bk = bucket_of(unorderable((u32)(key >> 32)));
      if (bk > T) {
        u32 base = (bk < 2047u) ? sfx[bk + 1] : 0u;
        u32 q = base + atomicAdd(&gcur[b * 2048 + bk], 1u);
        selB[q] = key;
      } else if (bk == T) {
        u32 q = atomicAdd(&cnt_mid[b], 1u);
        if (q < MIDCAP) midB[q] = key;             // ~45 expected with this data
      }
    }
  }
  grid.sync();                                     // ---- SYNC 2 ----

  // ---- C: per-wave bucket sort / midsel + fused gather. 128 waves per batch ----
  int gw = sub * 16 + wv;                          // [0,128)
  for (int i = gw; (int)T + i < 2048; i += BPB * 16) {
    int t = (int)T + i;
    u32 start, end;
    if (i == 0) {
      int need = PRE - (int)C1;
      int M = (int)cnt_mid[b]; if (M > MIDCAP) M = MIDCAP;
      for (int r = 0; r < need; ++r) {
        u64 best = 0; int bi = -1;
        for (int q = lane; q < M; q += 64) {
          u64 v = midB[q];
          if (v > best) { best = v; bi = q; }
        }
#pragma unroll
        for (int d = 32; d > 0; d >>= 1) {
          u64 ob = __shfl_xor(best, d, 64);
          int oi = __shfl_xor(bi, d, 64);
          if (ob > best) { best = ob; bi = oi; }
        }
        if (lane == 0) selB[C1 + r] = best;
        if (bi >= 0 && lane == (bi & 63)) midB[bi] = 0;  // remove chosen
      }
      start = C1; end = PRE;
    } else {
      start = (t < 2047) ? sfx[t + 1] : 0u;
      end = sfx[t];
      int n = (int)(end - start);
      if (n > 64) {
        // robustness fallback (never hit on bench data): selection sort
        for (int r = 0; r < n - 1; ++r) {
          u64 best = 0; int bi = -1;
          for (int q = r + lane; q < n; q += 64) {
            u64 v = selB[start + q];
            if (v > best) { best = v; bi = q; }
          }
#pragma unroll
          for (int d = 32; d > 0; d >>= 1) {
            u64 ob = __shfl_xor(best, d, 64);
            int oi = __shfl_xor(bi, d, 64);
            if (ob > best) { best = ob; bi = oi; }
          }
          if (lane == 0) {
            u64 tmp = selB[start + r];
            selB[start + r] = best;
            selB[start + bi] = tmp;
          }
        }
      } else if (n > 1) {
        u64 v = (lane < n) ? selB[start + lane] : 0ULL;  // MSB-set keys: pad sinks
#pragma unroll
        for (int k = 2; k <= 64; k <<= 1) {
#pragma unroll
          for (int j = k >> 1; j > 0; j >>= 1) {
            u64 o = __shfl_xor(v, j, 64);
            bool up = ((lane & k) == 0);
            bool first = ((lane & j) == 0);
            u64 mx = v > o ? v : o, mn = v > o ? o : v;
            v = (first == up) ? mx : mn;
          }
        }
        if (lane < n) selB[start + lane] = v;
      }
    }
    __builtin_amdgcn_s_waitcnt(0);                 // selB writes visible to this wave
    // fused gather for segment [start, end)
    for (u32 pos = start + lane; pos < end; pos += 64) {
      u64 key = selB[pos];
      u32 n = ~(u32)key;
      size_t src = (size_t)b * NN + n;
      const float* bx = boxes + src * 7;
      float x = bx[0], y = bx[1], dx = bx[3], dy = bx[4];
      size_t gidx = ((size_t)b << 12) + pos;
      float* tb = topBox + gidx * 7;
#pragma unroll
      for (int cc = 0; cc < 7; ++cc) tb[cc] = bx[cc];
      float4 p;
      p.x = x - 0.5f * dx; p.z = x + 0.5f * dx;    // 0.5*dx exact -> contraction-safe
      p.y = y - 0.5f * dy; p.w = y + 0.5f * dy;
      Pg[gidx] = p;
      ARg[gidx] = dx * dy;
      topS[gidx] = unorderable((u32)(key >> 32));
      topL[gidx] = labelsG[src];
    }
  }
  grid.sync();                                     // ---- SYNC 3 ----

  // ---- E: greedy NMS (one block per batch) vs LDS kept list ----
  if (sub != 0) return;                            // after last grid sync: safe to exit
  if (tid == 0) knSh = 0;
  if (tid < 64) kwLDS[tid] = 0;
  __syncthreads();
  size_t pb = (size_t)b << 12;
  for (int g = 0; g < 64; ++g) {
    int kn0 = (int)knSh;                           // stable since last barrier
    // 1. sup pass: wave wv owns candidates 4wv..4wv+3; 16 lanes split kept list
    int cj = g * 64 + 4 * wv + (lane >> 4);
    float4 cp = Pg[pb + cj];
    float car = ARg[pb + cj];
    bool hit = false; float mm = 1.0f;
    for (int m = (lane & 15); m < kn0; m += 16)
      hit |= iou_fast(keptP[m], keptAR[m], cp, car, mm);
    if (__any(mm <= 0.0f)) {                       // rare: exact-divide redo
      hit = false;
      for (int m = (lane & 15); m < kn0; m += 16)
        hit |= iou_exact(keptP[m], keptAR[m], cp, car);
    }
    u64 bal = __ballot(hit);
    int q = lane >> 4;
    if ((lane & 15) == 0)
      supArr[4 * wv + q] = (((bal >> (16 * q)) & 0xFFFFull) != 0ull) ? 1u : 0u;
    // 2. intra-group tile: wave wv computes rows 4wv..4wv+3 (lane = column)
    float4 cq = Pg[pb + g * 64 + lane];
    float cqa = ARg[pb + g * 64 + lane];
#pragma unroll
    for (int rr = 0; rr < 4; ++rr) {
      int rj = g * 64 + 4 * wv + rr;
      float4 rp = Pg[pb + rj];
      float rar = ARg[pb + rj];
      float mm2 = 1.0f;
      bool sup = iou_fast(rp, rar, cq, cqa, mm2);
      if (__any(mm2 <= 0.0f)) sup = iou_exact(rp, rar, cq, cqa);
      u64 dw = __ballot(sup);
      if (lane == 0) dLDS[4 * wv + rr] = dw;
    }
    __syncthreads();
    // 3. wave 0: sparse intra-group recurrence + append kept to LDS
    if (wv == 0) {
      u64 d_cur = dLDS[lane];
      u64 sup_word = __ballot(supArr[lane] != 0u);
      u64 aboveMask = ~((2ULL << lane) - 1ULL);    // lane=63 -> 0
      u64 rem = __ballot((d_cur & aboveMask) != 0ULL);
      if (rem) {                                   // rare: real intra suppressors
        do {
          int k = __ffsll((long long)rem) - 1;
          rem &= rem - 1;
          if (!((sup_word >> k) & 1ULL))           // row k kept -> apply bits >k
            sup_word |= readlane64(d_cur, k) & ~((2ULL << k) - 1ULL);
        } while (rem);
      }
      u64 keep = ~sup_word;
      int cnt = __popcll(keep);
      int rank = (int)__popcll(keep & ((1ULL << lane) - 1ULL));
      if ((keep >> lane) & 1ULL) {                 // kn0+rank <= 574 < KCAP
        int bi = g * 64 + lane;
        keptP[kn0 + rank] = Pg[pb + bi];
        keptAR[kn0 + rank] = ARg[pb + bi];
      }
      if (lane == 0) { kwLDS[g] = keep; knSh = (u32)(kn0 + cnt); }
    }
    __syncthreads();
    if (knSh >= POST) break;                       // uniform
  }

  // ---- finalize (wave 0): expand keep words, write output ----
  if (wv != 0) return;
  u64 kw = kwLDS[lane];
  int cnt = __popcll(kw);
  int pfx = cnt;
#pragma unroll
  for (int d = 1; d < 64; d <<= 1) {
    int up = __shfl_up(pfx, d, 64);
    if (lane >= d) pfx += up;
  }
  int total = __shfl(pfx, 63, 64);
  int pos = pfx - cnt;
  float* outR = out;
  float* outS = out + BB * POST * 7;
  float* outL = outS + BB * POST;
  while (kw) {
    int t = __ffsll((long long)kw) - 1;
    kw &= kw - 1;
    if (pos < POST) {
      int i = (lane << 6) + t;
      int gdx = (b << 9) + pos;
      const float* tb = topBox + (pb + i) * 7;
#pragma unroll
      for (int c = 0; c < 7; ++c) outR[(size_t)gdx * 7 + c] = tb[c];
      outS[gdx] = topS[pb + i];
      outL[gdx] = (float)(topL[pb + i] + 1);
    }
    ++pos;
  }
  int fin = total < POST ? total : POST;
  for (int s = fin + lane; s < POST; s += 64) {    // empty slots: 0 / 0 / label 1
    int gdx = (b << 9) + s;
#pragma unroll
    for (int c = 0; c < 7; ++c) outR[(size_t)gdx * 7 + c] = 0.0f;
    outS[gdx] = 0.0f;
    outL[gdx] = 1.0f;
  }
}

extern "C" void kernel_launch(void* const* d_in, const int* in_sizes, int n_in,
                              void* d_out, int out_size, void* d_ws, size_t ws_size,
                              hipStream_t stream) {
  const float* boxes = (const float*)d_in[0];   // (4,32768,7)
  const float* cls   = (const float*)d_in[1];   // (4,32768,3)
  float* out = (float*)d_out;

  // ---- workspace carve-up (~3.3 MB) ----
  char* p = (char*)d_ws;
  auto take = [&](size_t bytes) { char* r = p; p += (bytes + 255) & ~(size_t)255; return (void*)r; };
  u64*   keys    = (u64*)  take((size_t)BB * NN * 8);
  int*   labels  = (int*)  take((size_t)BB * NN * 4);
  u64*   sel     = (u64*)  take((size_t)BB * PRE * 8);
  u64*   mid     = (u64*)  take((size_t)BB * MIDCAP * 8);
  float4* Pg     = (float4*)take((size_t)BB * PRE * 16);
  float* ARg     = (float*)take((size_t)BB * PRE * 4);
  float* topBox  = (float*)take((size_t)BB * PRE * 7 * 4);
  float* topS    = (float*)take((size_t)BB * PRE * 4);
  int*   topL    = (int*)  take((size_t)BB * PRE * 4);
  u32*   gcur    = (u32*)  take((size_t)BB * 2048 * 4);
  u32*   cnt_mid = (u32*)  take((size_t)BB * 4);
  u32*   histP   = (u32*)  take((size_t)NBLK * 2048 * 4);

  void* args[] = {(void*)&boxes, (void*)&cls, (void*)&keys, (void*)&labels,
                  (void*)&sel, (void*)&mid, (void*)&Pg, (void*)&ARg,
                  (void*)&topBox, (void*)&topS, (void*)&topL,
                  (void*)&gcur, (void*)&cnt_mid, (void*)&histP, (void*)&out};
  hipLaunchCooperativeKernel((void*)nms_coop_kernel, dim3(NBLK), dim3(1024),
                             args, 0, stream);
}

// Round 20
// 113.575 us; speedup vs baseline: 1.0717x; 1.0717x over previous
//
#include <hip/hip_runtime.h>
#include <stdint.h>

#define BB 4
#define NN 32768
#define PRE 4096
#define POST 512
#define NMS_TH 0.7f
#define MIDCAP 8192
#define KCAP 576          // max kept before early-exit: 511 + 64

typedef unsigned long long u64;
typedef unsigned int u32;

__device__ __forceinline__ u32 orderable(float f) {
  u32 u = __float_as_uint(f);
  return (u & 0x80000000u) ? ~u : (u | 0x80000000u);
}
__device__ __forceinline__ float unorderable(u32 o) {
  u32 u = (o & 0x80000000u) ? (o & 0x7fffffffu) : ~o;
  return __uint_as_float(u);
}
// Monotone fixed-point bucket: uniform in score space (scores in [0,1)).
__device__ __forceinline__ u32 bucket_of(float s) {
  u32 v = (u32)(s * 2147483648.0f);
  u32 bk = v >> 20;
  return bk > 2047u ? 2047u : bk;
}
__device__ __forceinline__ u64 readlane64(u64 v, int l) {
  u32 lo = (u32)__builtin_amdgcn_readlane((int)(u32)v, l);
  u32 hi = (u32)__builtin_amdgcn_readlane((int)(u32)(v >> 32), l);
  return ((u64)hi << 32) | lo;
}
// IoU fast compare (threshold form) with margin tracking; exact-divide twin.
// Same op order as reference: denom = ((a1 + a2) - inter) + 1e-6.
__device__ __forceinline__ bool iou_fast(float4 a, float aa, float4 b, float ba, float& mm) {
  float ix = fminf(a.z, b.z) - fmaxf(a.x, b.x); ix = fmaxf(0.0f, ix);
  float iy = fminf(a.w, b.w) - fmaxf(a.y, b.y); iy = fmaxf(0.0f, iy);
  float inter = ix * iy;
  float denom = ((aa + ba) - inter) + 1e-6f;
  float t = 0.7f * denom;
  mm = fminf(mm, fabsf(inter - t) - 2e-5f * t);   // band >> max rounding skew (~4e-7)
  return inter > t;
}
__device__ __forceinline__ bool iou_exact(float4 a, float aa, float4 b, float ba) {
  float ix = fminf(a.z, b.z) - fmaxf(a.x, b.x); ix = fmaxf(0.0f, ix);
  float iy = fminf(a.w, b.w) - fmaxf(a.y, b.y); iy = fmaxf(0.0f, iy);
  float inter = ix * iy;
  float denom = ((aa + ba) - inter) + 1e-6f;
  return (inter / denom) > NMS_TH;
}

// score/label/key for 4 points per thread (vectorized). Per-block PARTIAL
// histogram with plain stores — no global atomics, no pre-zero, no fence.
__global__ __launch_bounds__(256) void score_hist_kernel(const float* __restrict__ cls,
                                                         int* __restrict__ labels,
                                                         u64* __restrict__ keys,
                                                         u32* __restrict__ histP) {
  __shared__ u32 lh[2048];
  for (int t = threadIdx.x; t < 2048; t += 256) lh[t] = 0;
  __syncthreads();
  int t4 = blockIdx.x * 256 + threadIdx.x;
  int base4 = t4 * 4;                               // first point id (batches 4-aligned)
  const float4* c4 = (const float4*)(cls + (size_t)t4 * 12);
  float4 va = c4[0], vb = c4[1], vc = c4[2];
  float v[12] = {va.x, va.y, va.z, va.w, vb.x, vb.y, vb.z, vb.w, vc.x, vc.y, vc.z, vc.w};
  u64 ks[4]; int ls[4];
#pragma unroll
  for (int p = 0; p < 4; ++p) {
    float s = v[3 * p]; int l = 0;
    if (v[3 * p + 1] > s) { s = v[3 * p + 1]; l = 1; }
    if (v[3 * p + 2] > s) { s = v[3 * p + 2]; l = 2; }
    int n = (base4 + p) & (NN - 1);
    ks[p] = ((u64)orderable(s) << 32) | (u32)(~(u32)n);
    ls[p] = l;
    atomicAdd(&lh[bucket_of(s)], 1u);
  }
  *(ulonglong2*)(keys + base4) = make_ulonglong2(ks[0], ks[1]);
  *(ulonglong2*)(keys + base4 + 2) = make_ulonglong2(ks[2], ks[3]);
  *(int4*)(labels + base4) = make_int4(ls[0], ls[1], ls[2], ls[3]);
  __syncthreads();
  u32* myrow = histP + (size_t)blockIdx.x * 2048;
  for (int t = threadIdx.x; t < 2048; t += 256) myrow[t] = lh[t];
}

// Per batch: sum the 32 partial histograms, suffix-scan, find threshold bucket
// T, init per-bucket cursors. Also zeroes this batch's mid counter.
__global__ __launch_bounds__(256) void select_kernel(const u32* __restrict__ histP,
                                                     u32* __restrict__ selinfo,
                                                     u32* __restrict__ sfxBuf,
                                                     u32* __restrict__ cursor,
                                                     u32* __restrict__ cnt_mid) {
  __shared__ u32 sfx[2048];
  int b = blockIdx.x;
  if (threadIdx.x == 0) cnt_mid[b] = 0;
  for (int t = threadIdx.x; t < 2048; t += 256) {
    u32 s = 0;
    const u32* pp = histP + (size_t)(b * 32) * 2048 + t;
#pragma unroll
    for (int j = 0; j < 32; ++j) s += pp[(size_t)j * 2048];
    sfx[t] = s;
  }
  __syncthreads();
  for (int d = 1; d < 2048; d <<= 1) {
    u32 v[8];
#pragma unroll
    for (int i = 0; i < 8; ++i) {
      int t = threadIdx.x + i * 256;
      v[i] = (t + d < 2048) ? sfx[t + d] : 0;
    }
    __syncthreads();
#pragma unroll
    for (int i = 0; i < 8; ++i) sfx[threadIdx.x + i * 256] += v[i];
    __syncthreads();
  }
  for (int t = threadIdx.x; t < 2048; t += 256) {
    u32 above = (t + 1 < 2048) ? sfx[t + 1] : 0;
    sfxBuf[b * 2048 + t] = sfx[t];
    cursor[b * 2048 + t] = above;                       // segment base
    if (above < PRE && sfx[t] >= PRE) { selinfo[b * 2] = (u32)t; selinfo[b * 2 + 1] = above; }
  }
}

// Compact, 4 keys/thread (2x ulonglong2 loads): hi keys scatter into their
// bucket's segment via per-bucket cursors; mid keys to the tie-break buffer.
__global__ __launch_bounds__(256) void compact_kernel(const u64* __restrict__ keys,
                                                      const u32* __restrict__ selinfo,
                                                      u32* __restrict__ cursor,
                                                      u64* __restrict__ sel, u64* __restrict__ mid,
                                                      u32* __restrict__ cnt_mid) {
  int t4 = blockIdx.x * 256 + threadIdx.x;
  int base4 = t4 * 4;
  int b = base4 >> 15;
  u32 T = selinfo[b * 2];
  ulonglong2 k01 = *(const ulonglong2*)(keys + base4);
  ulonglong2 k23 = *(const ulonglong2*)(keys + base4 + 2);
  u64 kk[4] = {k01.x, k01.y, k23.x, k23.y};
#pragma unroll
  for (int p = 0; p < 4; ++p) {
    u64 key = kk[p];
    u32 bk = bucket_of(unorderable((u32)(key >> 32)));
    if (bk > T) {
      u32 q = atomicAdd(&cursor[b * 2048 + bk], 1u);
      sel[((size_t)b << 12) + q] = key;
    } else if (bk == T) {
      u32 q = atomicAdd(&cnt_mid[b], 1u);
      if (q < MIDCAP) mid[(size_t)b * MIDCAP + q] = key;   // ~45 expected with this data
    }
  }
}

// One wave per (batch, bucket). Buckets > T: in-register 64-lane bitonic sort.
// Bucket == T: top (PRE-C1) mid keys by wave argmax (fused midsel). Then fused
// gather of ONLY what the NMS needs: P (bounds), AR, topS. Box payload/labels
// are fetched later for just the 512 kept.
__global__ __launch_bounds__(64) void bsort_kernel(u64* __restrict__ sel, u64* __restrict__ mid,
                                                   const u32* __restrict__ sfxBuf,
                                                   const u32* __restrict__ selinfo,
                                                   const u32* __restrict__ cnt_mid,
                                                   const float* __restrict__ boxes,
                                                   float4* __restrict__ P,
                                                   float* __restrict__ AR,
                                                   float* __restrict__ topS) {
  int t = blockIdx.x & 2047;
  int b = blockIdx.x >> 11;
  int lane = threadIdx.x;
  u32 T = selinfo[b * 2];
  if ((u32)t < T) return;
  u64* selB = sel + ((size_t)b << 12);
  u32 start, end;
  if ((u32)t == T) {
    u32 C1 = selinfo[b * 2 + 1];
    int need = PRE - (int)C1;
    int M = (int)cnt_mid[b]; if (M > MIDCAP) M = MIDCAP;
    u64* midB = mid + (size_t)b * MIDCAP;
    for (int r = 0; r < need; ++r) {
      u64 best = 0; int bi = -1;
      for (int q = lane; q < M; q += 64) {
        u64 v = midB[q];
        if (v > best) { best = v; bi = q; }
      }
#pragma unroll
      for (int d = 32; d > 0; d >>= 1) {
        u64 ob = __shfl_xor(best, d, 64);
        int oi = __shfl_xor(bi, d, 64);
        if (ob > best) { best = ob; bi = oi; }
      }
      if (lane == 0) selB[C1 + r] = best;
      if (bi >= 0 && lane == (bi & 63)) midB[bi] = 0;    // remove chosen
    }
    start = C1; end = PRE;
  } else {
    start = (t < 2047) ? sfxBuf[b * 2048 + t + 1] : 0u;
    end = sfxBuf[b * 2048 + t];
    int n = (int)(end - start);
    if (n > 64) {
      // robustness fallback (never hit on bench data): selection sort
      for (int r = 0; r < n - 1; ++r) {
        u64 best = 0; int bi = -1;
        for (int q = r + lane; q < n; q += 64) {
          u64 v = selB[start + q];
          if (v > best) { best = v; bi = q; }
        }
#pragma unroll
        for (int d = 32; d > 0; d >>= 1) {
          u64 ob = __shfl_xor(best, d, 64);
          int oi = __shfl_xor(bi, d, 64);
          if (ob > best) { best = ob; bi = oi; }
        }
        if (lane == 0) {
          u64 tmp = selB[start + r];
          selB[start + r] = best;
          selB[start + bi] = tmp;
        }
      }
    } else if (n > 1) {
      u64 v = (lane < n) ? selB[start + lane] : 0ULL;    // MSB-set keys: pad sinks
#pragma unroll
      for (int k = 2; k <= 64; k <<= 1) {
#pragma unroll
        for (int j = k >> 1; j > 0; j >>= 1) {
          u64 o = __shfl_xor(v, j, 64);
          bool up = ((lane & k) == 0);
          bool first = ((lane & j) == 0);
          u64 mx = v > o ? v : o, mn = v > o ? o : v;
          v = (first == up) ? mx : mn;
        }
      }
      if (lane < n) selB[start + lane] = v;
    }
  }
  __builtin_amdgcn_s_waitcnt(0);                         // selB writes visible to this wave
  // ---- fused gather (P/AR/topS only) for segment [start, end) ----
  for (u32 pos = start + lane; pos < end; pos += 64) {
    u64 key = selB[pos];
    u32 n = ~(u32)key;
    const float* bx = boxes + ((size_t)b * NN + n) * 7;
    float x = bx[0], y = bx[1], dx = bx[3], dy = bx[4];
    size_t gidx = ((size_t)b << 12) + pos;
    float4 p;
    p.x = x - 0.5f * dx; p.z = x + 0.5f * dx;   // 0.5*dx exact -> contraction-safe
    p.y = y - 0.5f * dy; p.w = y + 0.5f * dy;
    P[gidx] = p;
    AR[gidx] = dx * dy;
    topS[gidx] = unorderable((u32)(key >> 32));
  }
}

// Greedy NMS directly vs the LDS kept list (no mask matrix) + finalize.
// One block (16 waves) per batch. Verified logic from R18/R19 phase E.
__global__ __launch_bounds__(1024, 1) void nms_final_kernel(
    const float4* __restrict__ Pg, const float* __restrict__ ARg,
    const float* __restrict__ topS, const u64* __restrict__ selG,
    const float* __restrict__ boxes, const int* __restrict__ labels,
    float* __restrict__ out) {
  __shared__ float4 keptP[KCAP];
  __shared__ float keptAR[KCAP];
  __shared__ u64 dLDS[64];
  __shared__ u64 kwLDS[64];
  __shared__ u32 supArr[64];
  __shared__ u32 knSh;
  int b = blockIdx.x;
  int tid = threadIdx.x;
  int wv = tid >> 6, lane = tid & 63;
  if (tid == 0) knSh = 0;
  if (tid < 64) kwLDS[tid] = 0;
  __syncthreads();
  size_t pb = (size_t)b << 12;
  for (int g = 0; g < 64; ++g) {
    int kn0 = (int)knSh;                           // stable since last barrier
    // 1. sup pass: wave wv owns candidates 4wv..4wv+3; 16 lanes split kept list
    int cj = g * 64 + 4 * wv + (lane >> 4);
    float4 cp = Pg[pb + cj];
    float car = ARg[pb + cj];
    bool hit = false; float mm = 1.0f;
    for (int m = (lane & 15); m < kn0; m += 16)
      hit |= iou_fast(keptP[m], keptAR[m], cp, car, mm);
    if (__any(mm <= 0.0f)) {                       // rare: exact-divide redo
      hit = false;
      for (int m = (lane & 15); m < kn0; m += 16)
        hit |= iou_exact(keptP[m], keptAR[m], cp, car);
    }
    u64 bal = __ballot(hit);
    int q = lane >> 4;
    if ((lane & 15) == 0)
      supArr[4 * wv + q] = (((bal >> (16 * q)) & 0xFFFFull) != 0ull) ? 1u : 0u;
    // 2. intra-group tile: wave wv computes rows 4wv..4wv+3 (lane = column)
    float4 cq = Pg[pb + g * 64 + lane];
    float cqa = ARg[pb + g * 64 + lane];
#pragma unroll
    for (int rr = 0; rr < 4; ++rr) {
      int rj = g * 64 + 4 * wv + rr;
      float4 rp = Pg[pb + rj];
      float rar = ARg[pb + rj];
      float mm2 = 1.0f;
      bool sup = iou_fast(rp, rar, cq, cqa, mm2);
      if (__any(mm2 <= 0.0f)) sup = iou_exact(rp, rar, cq, cqa);
      u64 dw = __ballot(sup);
      if (lane == 0) dLDS[4 * wv + rr] = dw;
    }
    __syncthreads();
    // 3. wave 0: sparse intra-group recurrence + append kept to LDS
    if (wv == 0) {
      u64 d_cur = dLDS[lane];
      u64 sup_word = __ballot(supArr[lane] != 0u);
      u64 aboveMask = ~((2ULL << lane) - 1ULL);    // lane=63 -> 0
      u64 rem = __ballot((d_cur & aboveMask) != 0ULL);
      if (rem) {                                   // rare: real intra suppressors
        do {
          int k = __ffsll((long long)rem) - 1;
          rem &= rem - 1;
          if (!((sup_word >> k) & 1ULL))           // row k kept -> apply bits >k
            sup_word |= readlane64(d_cur, k) & ~((2ULL << k) - 1ULL);
        } while (rem);
      }
      u64 keep = ~sup_word;
      int cnt = __popcll(keep);
      int rank = (int)__popcll(keep & ((1ULL << lane) - 1ULL));
      if ((keep >> lane) & 1ULL) {                 // kn0+rank <= 574 < KCAP
        int bi = g * 64 + lane;
        keptP[kn0 + rank] = Pg[pb + bi];
        keptAR[kn0 + rank] = ARg[pb + bi];
      }
      if (lane == 0) { kwLDS[g] = keep; knSh = (u32)(kn0 + cnt); }
    }
    __syncthreads();
    if (knSh >= POST) break;                       // uniform
  }
  // ---- finalize (wave 0): expand keep words; fetch box payload for kept only ----
  if (wv != 0) return;
  u64 kw = kwLDS[lane];
  int cnt = __popcll(kw);
  int pfx = cnt;
#pragma unroll
  for (int d = 1; d < 64; d <<= 1) {
    int up = __shfl_up(pfx, d, 64);
    if (lane >= d) pfx += up;
  }
  int total = __shfl(pfx, 63, 64);
  int pos = pfx - cnt;
  float* outR = out;
  float* outS = out + BB * POST * 7;
  float* outL = outS + BB * POST;
  while (kw) {
    int t = __ffsll((long long)kw) - 1;
    kw &= kw - 1;
    if (pos < POST) {
      int i = (lane << 6) + t;
      int gdx = (b << 9) + pos;
      u64 key = selG[pb + i];
      u32 n = ~(u32)key;
      size_t src = (size_t)b * NN + n;
      const float* bx = boxes + src * 7;
#pragma unroll
      for (int c = 0; c < 7; ++c) outR[(size_t)gdx * 7 + c] = bx[c];
      outS[gdx] = topS[pb + i];
      outL[gdx] = (float)(labels[src] + 1);
    }
    ++pos;
  }
  int fin = total < POST ? total : POST;
  for (int s = fin + lane; s < POST; s += 64) {    // empty slots: 0 / 0 / label 1
    int gdx = (b << 9) + s;
#pragma unroll
    for (int c = 0; c < 7; ++c) outR[(size_t)gdx * 7 + c] = 0.0f;
    outS[gdx] = 0.0f;
    outL[gdx] = 1.0f;
  }
}

extern "C" void kernel_launch(void* const* d_in, const int* in_sizes, int n_in,
                              void* d_out, int out_size, void* d_ws, size_t ws_size,
                              hipStream_t stream) {
  const float* boxes = (const float*)d_in[0];   // (4,32768,7)
  const float* cls   = (const float*)d_in[1];   // (4,32768,3)
  float* out = (float*)d_out;

  // ---- workspace carve-up (~3 MB) ----
  char* p = (char*)d_ws;
  auto take = [&](size_t bytes) { char* r = p; p += (bytes + 255) & ~(size_t)255; return (void*)r; };
  u64*   keys    = (u64*)  take((size_t)BB * NN * 8);
  int*   labels  = (int*)  take((size_t)BB * NN * 4);
  u32*   histP   = (u32*)  take((size_t)BB * 32 * 2048 * 4);   // per-block partials
  u32*   selinfo = (u32*)  take((size_t)BB * 2 * 4);
  u32*   sfxBuf  = (u32*)  take((size_t)BB * 2048 * 4);
  u32*   cursor  = (u32*)  take((size_t)BB * 2048 * 4);
  u32*   cnt_mid = (u32*)  take((size_t)BB * 4);
  u64*   sel     = (u64*)  take((size_t)BB * PRE * 8);
  u64*   mid     = (u64*)  take((size_t)BB * MIDCAP * 8);
  float4* Pg     = (float4*)take((size_t)BB * PRE * 16);
  float* ARg     = (float*)take((size_t)BB * PRE * 4);
  float* topS    = (float*)take((size_t)BB * PRE * 4);

  score_hist_kernel<<<BB * NN / 1024, 256, 0, stream>>>(cls, labels, keys, histP);
  select_kernel<<<BB, 256, 0, stream>>>(histP, selinfo, sfxBuf, cursor, cnt_mid);
  compact_kernel<<<BB * NN / 1024, 256, 0, stream>>>(keys, selinfo, cursor, sel, mid, cnt_mid);
  bsort_kernel<<<BB * 2048, 64, 0, stream>>>(sel, mid, sfxBuf, selinfo, cnt_mid,
                                             boxes, Pg, ARg, topS);
  nms_final_kernel<<<BB, 1024, 0, stream>>>(Pg, ARg, topS, sel, boxes, labels, out);
}

// Round 21
// 94.112 us; speedup vs baseline: 1.2933x; 1.2068x over previous
//
#include <hip/hip_runtime.h>
#include <stdint.h>

#define BB 4
#define NN 32768
#define PRE 4096
#define POST 512
#define NMS_TH 0.7f
#define MIDCAP 8192
#define KCAP 576          // max kept before early-exit: 511 + 64
#define LROWS 1024        // rows staged in LDS (groups 0..15)

typedef unsigned long long u64;
typedef unsigned int u32;

__device__ __forceinline__ u32 orderable(float f) {
  u32 u = __float_as_uint(f);
  return (u & 0x80000000u) ? ~u : (u | 0x80000000u);
}
__device__ __forceinline__ float unorderable(u32 o) {
  u32 u = (o & 0x80000000u) ? (o & 0x7fffffffu) : ~o;
  return __uint_as_float(u);
}
// Monotone fixed-point bucket: uniform in score space (scores in [0,1)).
__device__ __forceinline__ u32 bucket_of(float s) {
  u32 v = (u32)(s * 2147483648.0f);
  u32 bk = v >> 20;
  return bk > 2047u ? 2047u : bk;
}
__device__ __forceinline__ u64 readlane64(u64 v, int l) {
  u32 lo = (u32)__builtin_amdgcn_readlane((int)(u32)v, l);
  u32 hi = (u32)__builtin_amdgcn_readlane((int)(u32)(v >> 32), l);
  return ((u64)hi << 32) | lo;
}
// IoU fast compare (threshold form) with margin tracking; exact-divide twin.
// Same op order as reference: denom = ((a1 + a2) - inter) + 1e-6.
__device__ __forceinline__ bool iou_fast(float4 a, float aa, float4 b, float ba, float& mm) {
  float ix = fminf(a.z, b.z) - fmaxf(a.x, b.x); ix = fmaxf(0.0f, ix);
  float iy = fminf(a.w, b.w) - fmaxf(a.y, b.y); iy = fmaxf(0.0f, iy);
  float inter = ix * iy;
  float denom = ((aa + ba) - inter) + 1e-6f;
  float t = 0.7f * denom;
  mm = fminf(mm, fabsf(inter - t) - 2e-5f * t);   // band >> max rounding skew (~4e-7)
  return inter > t;
}
__device__ __forceinline__ bool iou_exact(float4 a, float aa, float4 b, float ba) {
  float ix = fminf(a.z, b.z) - fmaxf(a.x, b.x); ix = fmaxf(0.0f, ix);
  float iy = fminf(a.w, b.w) - fmaxf(a.y, b.y); iy = fmaxf(0.0f, iy);
  float inter = ix * iy;
  float denom = ((aa + ba) - inter) + 1e-6f;
  return (inter / denom) > NMS_TH;
}

// score/label/key for 4 points per thread (vectorized). Per-block PARTIAL
// histogram with plain stores — no global atomics, no pre-zero, no fence.
__global__ __launch_bounds__(256) void score_hist_kernel(const float* __restrict__ cls,
                                                         int* __restrict__ labels,
                                                         u64* __restrict__ keys,
                                                         u32* __restrict__ histP) {
  __shared__ u32 lh[2048];
  for (int t = threadIdx.x; t < 2048; t += 256) lh[t] = 0;
  __syncthreads();
  int t4 = blockIdx.x * 256 + threadIdx.x;
  int base4 = t4 * 4;                               // first point id (batches 4-aligned)
  const float4* c4 = (const float4*)(cls + (size_t)t4 * 12);
  float4 va = c4[0], vb = c4[1], vc = c4[2];
  float v[12] = {va.x, va.y, va.z, va.w, vb.x, vb.y, vb.z, vb.w, vc.x, vc.y, vc.z, vc.w};
  u64 ks[4]; int ls[4];
#pragma unroll
  for (int p = 0; p < 4; ++p) {
    float s = v[3 * p]; int l = 0;
    if (v[3 * p + 1] > s) { s = v[3 * p + 1]; l = 1; }
    if (v[3 * p + 2] > s) { s = v[3 * p + 2]; l = 2; }
    int n = (base4 + p) & (NN - 1);
    ks[p] = ((u64)orderable(s) << 32) | (u32)(~(u32)n);
    ls[p] = l;
    atomicAdd(&lh[bucket_of(s)], 1u);
  }
  *(ulonglong2*)(keys + base4) = make_ulonglong2(ks[0], ks[1]);
  *(ulonglong2*)(keys + base4 + 2) = make_ulonglong2(ks[2], ks[3]);
  *(int4*)(labels + base4) = make_int4(ls[0], ls[1], ls[2], ls[3]);
  __syncthreads();
  u32* myrow = histP + (size_t)blockIdx.x * 2048;
  for (int t = threadIdx.x; t < 2048; t += 256) myrow[t] = lh[t];
}

// Per batch: sum the 32 partial histograms, suffix-scan, find threshold bucket
// T, init per-bucket cursors. Also zeroes this batch's mid counter.
__global__ __launch_bounds__(256) void select_kernel(const u32* __restrict__ histP,
                                                     u32* __restrict__ selinfo,
                                                     u32* __restrict__ sfxBuf,
                                                     u32* __restrict__ cursor,
                                                     u32* __restrict__ cnt_mid) {
  __shared__ u32 sfx[2048];
  int b = blockIdx.x;
  if (threadIdx.x == 0) cnt_mid[b] = 0;
  for (int t = threadIdx.x; t < 2048; t += 256) {
    u32 s = 0;
    const u32* pp = histP + (size_t)(b * 32) * 2048 + t;
#pragma unroll
    for (int j = 0; j < 32; ++j) s += pp[(size_t)j * 2048];
    sfx[t] = s;
  }
  __syncthreads();
  for (int d = 1; d < 2048; d <<= 1) {
    u32 v[8];
#pragma unroll
    for (int i = 0; i < 8; ++i) {
      int t = threadIdx.x + i * 256;
      v[i] = (t + d < 2048) ? sfx[t + d] : 0;
    }
    __syncthreads();
#pragma unroll
    for (int i = 0; i < 8; ++i) sfx[threadIdx.x + i * 256] += v[i];
    __syncthreads();
  }
  for (int t = threadIdx.x; t < 2048; t += 256) {
    u32 above = (t + 1 < 2048) ? sfx[t + 1] : 0;
    sfxBuf[b * 2048 + t] = sfx[t];
    cursor[b * 2048 + t] = above;                       // segment base
    if (above < PRE && sfx[t] >= PRE) { selinfo[b * 2] = (u32)t; selinfo[b * 2 + 1] = above; }
  }
}

// Compact, 4 keys/thread (2x ulonglong2 loads): hi keys scatter into their
// bucket's segment via per-bucket cursors; mid keys to the tie-break buffer.
__global__ __launch_bounds__(256) void compact_kernel(const u64* __restrict__ keys,
                                                      const u32* __restrict__ selinfo,
                                                      u32* __restrict__ cursor,
                                                      u64* __restrict__ sel, u64* __restrict__ mid,
                                                      u32* __restrict__ cnt_mid) {
  int t4 = blockIdx.x * 256 + threadIdx.x;
  int base4 = t4 * 4;
  int b = base4 >> 15;
  u32 T = selinfo[b * 2];
  ulonglong2 k01 = *(const ulonglong2*)(keys + base4);
  ulonglong2 k23 = *(const ulonglong2*)(keys + base4 + 2);
  u64 kk[4] = {k01.x, k01.y, k23.x, k23.y};
#pragma unroll
  for (int p = 0; p < 4; ++p) {
    u64 key = kk[p];
    u32 bk = bucket_of(unorderable((u32)(key >> 32)));
    if (bk > T) {
      u32 q = atomicAdd(&cursor[b * 2048 + bk], 1u);
      sel[((size_t)b << 12) + q] = key;
    } else if (bk == T) {
      u32 q = atomicAdd(&cnt_mid[b], 1u);
      if (q < MIDCAP) mid[(size_t)b * MIDCAP + q] = key;   // ~45 expected with this data
    }
  }
}

// One wave per (batch, bucket). Buckets > T: in-register 64-lane bitonic sort.
// Bucket == T: top (PRE-C1) mid keys by wave argmax (fused midsel). Then fused
// gather of ONLY what the NMS needs: P (bounds), AR, topS.
__global__ __launch_bounds__(64) void bsort_kernel(u64* __restrict__ sel, u64* __restrict__ mid,
                                                   const u32* __restrict__ sfxBuf,
                                                   const u32* __restrict__ selinfo,
                                                   const u32* __restrict__ cnt_mid,
                                                   const float* __restrict__ boxes,
                                                   float4* __restrict__ P,
                                                   float* __restrict__ AR,
                                                   float* __restrict__ topS) {
  int t = blockIdx.x & 2047;
  int b = blockIdx.x >> 11;
  int lane = threadIdx.x;
  u32 T = selinfo[b * 2];
  if ((u32)t < T) return;
  u64* selB = sel + ((size_t)b << 12);
  u32 start, end;
  if ((u32)t == T) {
    u32 C1 = selinfo[b * 2 + 1];
    int need = PRE - (int)C1;
    int M = (int)cnt_mid[b]; if (M > MIDCAP) M = MIDCAP;
    u64* midB = mid + (size_t)b * MIDCAP;
    for (int r = 0; r < need; ++r) {
      u64 best = 0; int bi = -1;
      for (int q = lane; q < M; q += 64) {
        u64 v = midB[q];
        if (v > best) { best = v; bi = q; }
      }
#pragma unroll
      for (int d = 32; d > 0; d >>= 1) {
        u64 ob = __shfl_xor(best, d, 64);
        int oi = __shfl_xor(bi, d, 64);
        if (ob > best) { best = ob; bi = oi; }
      }
      if (lane == 0) selB[C1 + r] = best;
      if (bi >= 0 && lane == (bi & 63)) midB[bi] = 0;    // remove chosen
    }
    start = C1; end = PRE;
  } else {
    start = (t < 2047) ? sfxBuf[b * 2048 + t + 1] : 0u;
    end = sfxBuf[b * 2048 + t];
    int n = (int)(end - start);
    if (n > 64) {
      // robustness fallback (never hit on bench data): selection sort
      for (int r = 0; r < n - 1; ++r) {
        u64 best = 0; int bi = -1;
        for (int q = r + lane; q < n; q += 64) {
          u64 v = selB[start + q];
          if (v > best) { best = v; bi = q; }
        }
#pragma unroll
        for (int d = 32; d > 0; d >>= 1) {
          u64 ob = __shfl_xor(best, d, 64);
          int oi = __shfl_xor(bi, d, 64);
          if (ob > best) { best = ob; bi = oi; }
        }
        if (lane == 0) {
          u64 tmp = selB[start + r];
          selB[start + r] = best;
          selB[start + bi] = tmp;
        }
      }
    } else if (n > 1) {
      u64 v = (lane < n) ? selB[start + lane] : 0ULL;    // MSB-set keys: pad sinks
#pragma unroll
      for (int k = 2; k <= 64; k <<= 1) {
#pragma unroll
        for (int j = k >> 1; j > 0; j >>= 1) {
          u64 o = __shfl_xor(v, j, 64);
          bool up = ((lane & k) == 0);
          bool first = ((lane & j) == 0);
          u64 mx = v > o ? v : o, mn = v > o ? o : v;
          v = (first == up) ? mx : mn;
        }
      }
      if (lane < n) selB[start + lane] = v;
    }
  }
  __builtin_amdgcn_s_waitcnt(0);                         // selB writes visible to this wave
  // ---- fused gather (P/AR/topS only) for segment [start, end) ----
  for (u32 pos = start + lane; pos < end; pos += 64) {
    u64 key = selB[pos];
    u32 n = ~(u32)key;
    const float* bx = boxes + ((size_t)b * NN + n) * 7;
    float x = bx[0], y = bx[1], dx = bx[3], dy = bx[4];
    size_t gidx = ((size_t)b << 12) + pos;
    float4 p;
    p.x = x - 0.5f * dx; p.z = x + 0.5f * dx;   // 0.5*dx exact -> contraction-safe
    p.y = y - 0.5f * dy; p.w = y + 0.5f * dy;
    P[gidx] = p;
    AR[gidx] = dx * dy;
    topS[gidx] = unorderable((u32)(key >> 32));
  }
}

// Greedy NMS vs LDS kept list + parallel finalize. One block (16 waves)/batch.
// R21 latency fixes vs R20 (logic identical): (a) rows 0..1023 staged in LDS
// (group loop touches no global memory; fallback to global for groups >= 16
// keeps exactness); (b) kept-scan manually unrolled x4 (OR/min reductions are
// order-independent -> 4 loads in flight); (c) finalize spread over all 1024
// threads via an LDS keptIdx (one latency round, not 8 serialized on 1 wave).
__global__ __launch_bounds__(1024, 1) void nms_final_kernel(
    const float4* __restrict__ Pg, const float* __restrict__ ARg,
    const float* __restrict__ topS, const u64* __restrict__ selG,
    const float* __restrict__ boxes, const int* __restrict__ labels,
    float* __restrict__ out) {
  __shared__ float4 ldsP[LROWS];
  __shared__ float ldsAR[LROWS];
  __shared__ float4 keptP[KCAP];
  __shared__ float keptAR[KCAP];
  __shared__ u64 dLDS[64];
  __shared__ u64 kwLDS[64];
  __shared__ u32 supArr[64];
  __shared__ int keptIdx[POST];
  __shared__ u32 knSh, finSh, nGrpSh;
  int b = blockIdx.x;
  int tid = threadIdx.x;
  int wv = tid >> 6, lane = tid & 63;
  size_t pb = (size_t)b << 12;
  // stage first 1024 rows to LDS (one coalesced round)
  ldsP[tid] = Pg[pb + tid];
  ldsAR[tid] = ARg[pb + tid];
  if (tid == 0) knSh = 0;
  if (tid < 64) kwLDS[tid] = 0;
  __syncthreads();
  int gEnd = 0;
  for (int g = 0; g < 64; ++g) {
    gEnd = g + 1;
    int kn0 = (int)knSh;                           // stable since last barrier
    // 1. sup pass: wave wv owns candidates 4wv..4wv+3; 16 lanes split kept list
    int cj = g * 64 + 4 * wv + (lane >> 4);
    float4 cp; float car;
    if (cj < LROWS) { cp = ldsP[cj]; car = ldsAR[cj]; }
    else { cp = Pg[pb + cj]; car = ARg[pb + cj]; }
    bool hit = false; float mm = 1.0f;
    int m = lane & 15;
    for (; m + 48 < kn0; m += 64) {                // x4 unroll: 4 loads in flight
      hit |= iou_fast(keptP[m], keptAR[m], cp, car, mm);
      hit |= iou_fast(keptP[m + 16], keptAR[m + 16], cp, car, mm);
      hit |= iou_fast(keptP[m + 32], keptAR[m + 32], cp, car, mm);
      hit |= iou_fast(keptP[m + 48], keptAR[m + 48], cp, car, mm);
    }
    for (; m < kn0; m += 16)
      hit |= iou_fast(keptP[m], keptAR[m], cp, car, mm);
    if (__any(mm <= 0.0f)) {                       // rare: exact-divide redo
      hit = false;
      for (int m2 = (lane & 15); m2 < kn0; m2 += 16)
        hit |= iou_exact(keptP[m2], keptAR[m2], cp, car);
    }
    u64 bal = __ballot(hit);
    int q = lane >> 4;
    if ((lane & 15) == 0)
      supArr[4 * wv + q] = (((bal >> (16 * q)) & 0xFFFFull) != 0ull) ? 1u : 0u;
    // 2. intra-group tile: wave wv computes rows 4wv..4wv+3 (lane = column)
    int colj = g * 64 + lane;
    float4 cq; float cqa;
    if (colj < LROWS) { cq = ldsP[colj]; cqa = ldsAR[colj]; }
    else { cq = Pg[pb + colj]; cqa = ARg[pb + colj]; }
#pragma unroll
    for (int rr = 0; rr < 4; ++rr) {
      int rj = g * 64 + 4 * wv + rr;
      float4 rp; float rar;
      if (rj < LROWS) { rp = ldsP[rj]; rar = ldsAR[rj]; }
      else { rp = Pg[pb + rj]; rar = ARg[pb + rj]; }
      float mm2 = 1.0f;
      bool sup = iou_fast(rp, rar, cq, cqa, mm2);
      if (__any(mm2 <= 0.0f)) sup = iou_exact(rp, rar, cq, cqa);
      u64 dw = __ballot(sup);
      if (lane == 0) dLDS[4 * wv + rr] = dw;
    }
    __syncthreads();
    // 3. wave 0: sparse intra-group recurrence + append kept to LDS
    if (wv == 0) {
      u64 d_cur = dLDS[lane];
      u64 sup_word = __ballot(supArr[lane] != 0u);
      u64 aboveMask = ~((2ULL << lane) - 1ULL);    // lane=63 -> 0
      u64 rem = __ballot((d_cur & aboveMask) != 0ULL);
      if (rem) {                                   // rare: real intra suppressors
        do {
          int k = __ffsll((long long)rem) - 1;
          rem &= rem - 1;
          if (!((sup_word >> k) & 1ULL))           // row k kept -> apply bits >k
            sup_word |= readlane64(d_cur, k) & ~((2ULL << k) - 1ULL);
        } while (rem);
      }
      u64 keep = ~sup_word;
      int cnt = __popcll(keep);
      int rank = (int)__popcll(keep & ((1ULL << lane) - 1ULL));
      if ((keep >> lane) & 1ULL) {                 // kn0+rank <= 574 < KCAP
        int bi = g * 64 + lane;
        if (bi < LROWS) { keptP[kn0 + rank] = ldsP[bi]; keptAR[kn0 + rank] = ldsAR[bi]; }
        else { keptP[kn0 + rank] = Pg[pb + bi]; keptAR[kn0 + rank] = ARg[pb + bi]; }
      }
      if (lane == 0) { kwLDS[g] = keep; knSh = (u32)(kn0 + cnt); }
    }
    __syncthreads();
    if (knSh >= POST) break;                       // uniform
  }
  // ---- finalize stage 1 (wave 0): expand keep words into LDS keptIdx ----
  if (wv == 0) {
    u64 kw = kwLDS[lane];
    int cnt = __popcll(kw);
    int pfx = cnt;
#pragma unroll
    for (int d = 1; d < 64; d <<= 1) {
      int up = __shfl_up(pfx, d, 64);
      if (lane >= d) pfx += up;
    }
    int total = __shfl(pfx, 63, 64);
    int pos = pfx - cnt;
    while (kw) {
      int t = __ffsll((long long)kw) - 1;
      kw &= kw - 1;
      if (pos < POST) keptIdx[pos] = (lane << 6) + t;
      ++pos;
    }
    if (lane == 0) finSh = (u32)(total < POST ? total : POST);
  }
  __syncthreads();
  // ---- finalize stage 2 (all 1024 threads): write the 512 output slots ----
  int fin = (int)finSh;
  float* outR = out;
  float* outS = out + BB * POST * 7;
  float* outL = outS + BB * POST;
  for (int s = tid; s < POST; s += 1024) {
    int gdx = (b << 9) + s;
    if (s < fin) {
      int i = keptIdx[s];
      u64 key = selG[pb + i];
      u32 n = ~(u32)key;
      size_t src = (size_t)b * NN + n;
      const float* bx = boxes + src * 7;
#pragma unroll
      for (int c = 0; c < 7; ++c) outR[(size_t)gdx * 7 + c] = bx[c];
      outS[gdx] = topS[pb + i];
      outL[gdx] = (float)(labels[src] + 1);
    } else {                                       // empty slots: 0 / 0 / label 1
#pragma unroll
      for (int c = 0; c < 7; ++c) outR[(size_t)gdx * 7 + c] = 0.0f;
      outS[gdx] = 0.0f;
      outL[gdx] = 1.0f;
    }
  }
  (void)gEnd;
}

extern "C" void kernel_launch(void* const* d_in, const int* in_sizes, int n_in,
                              void* d_out, int out_size, void* d_ws, size_t ws_size,
                              hipStream_t stream) {
  const float* boxes = (const float*)d_in[0];   // (4,32768,7)
  const float* cls   = (const float*)d_in[1];   // (4,32768,3)
  float* out = (float*)d_out;

  // ---- workspace carve-up (~2.5 MB) ----
  char* p = (char*)d_ws;
  auto take = [&](size_t bytes) { char* r = p; p += (bytes + 255) & ~(size_t)255; return (void*)r; };
  u64*   keys    = (u64*)  take((size_t)BB * NN * 8);
  int*   labels  = (int*)  take((size_t)BB * NN * 4);
  u32*   histP   = (u32*)  take((size_t)BB * 32 * 2048 * 4);   // per-block partials
  u32*   selinfo = (u32*)  take((size_t)BB * 2 * 4);
  u32*   sfxBuf  = (u32*)  take((size_t)BB * 2048 * 4);
  u32*   cursor  = (u32*)  take((size_t)BB * 2048 * 4);
  u32*   cnt_mid = (u32*)  take((size_t)BB * 4);
  u64*   sel     = (u64*)  take((size_t)BB * PRE * 8);
  u64*   mid     = (u64*)  take((size_t)BB * MIDCAP * 8);
  float4* Pg     = (float4*)take((size_t)BB * PRE * 16);
  float* ARg     = (float*)take((size_t)BB * PRE * 4);
  float* topS    = (float*)take((size_t)BB * PRE * 4);

  score_hist_kernel<<<BB * NN / 1024, 256, 0, stream>>>(cls, labels, keys, histP);
  select_kernel<<<BB, 256, 0, stream>>>(histP, selinfo, sfxBuf, cursor, cnt_mid);
  compact_kernel<<<BB * NN / 1024, 256, 0, stream>>>(keys, selinfo, cursor, sel, mid, cnt_mid);
  bsort_kernel<<<BB * 2048, 64, 0, stream>>>(sel, mid, sfxBuf, selinfo, cnt_mid,
                                             boxes, Pg, ARg, topS);
  nms_final_kernel<<<BB, 1024, 0, stream>>>(Pg, ARg, topS, sel, boxes, labels, out);
}

// Round 22
// 93.769 us; speedup vs baseline: 1.2980x; 1.0037x over previous
//
#include <hip/hip_runtime.h>
#include <stdint.h>

#define BB 4
#define NN 32768
#define PRE 4096
#define POST 512
#define NMS_TH 0.7f
#define MIDCAP 8192
#define KCAP 576          // max kept before early-exit: 511 + 64
#define LROWS 1024        // rows staged in LDS (groups 0..15)
#define BGRID 18          // spatial hash: 18x18 bins of width 4 over [0,72]
#define BINS (BGRID * BGRID)
#define BCAP 16           // entries per bin before full-scan fallback

typedef unsigned long long u64;
typedef unsigned int u32;
typedef unsigned short u16;

__device__ __forceinline__ u32 orderable(float f) {
  u32 u = __float_as_uint(f);
  return (u & 0x80000000u) ? ~u : (u | 0x80000000u);
}
__device__ __forceinline__ float unorderable(u32 o) {
  u32 u = (o & 0x80000000u) ? (o & 0x7fffffffu) : ~o;
  return __uint_as_float(u);
}
// Monotone fixed-point bucket: uniform in score space (scores in [0,1)).
__device__ __forceinline__ u32 bucket_of(float s) {
  u32 v = (u32)(s * 2147483648.0f);
  u32 bk = v >> 20;
  return bk > 2047u ? 2047u : bk;
}
__device__ __forceinline__ u64 readlane64(u64 v, int l) {
  u32 lo = (u32)__builtin_amdgcn_readlane((int)(u32)v, l);
  u32 hi = (u32)__builtin_amdgcn_readlane((int)(u32)(v >> 32), l);
  return ((u64)hi << 32) | lo;
}
// IoU fast compare (threshold form) with margin tracking; exact-divide twin.
// Same op order as reference: denom = ((a1 + a2) - inter) + 1e-6.
__device__ __forceinline__ bool iou_fast(float4 a, float aa, float4 b, float ba, float& mm) {
  float ix = fminf(a.z, b.z) - fmaxf(a.x, b.x); ix = fmaxf(0.0f, ix);
  float iy = fminf(a.w, b.w) - fmaxf(a.y, b.y); iy = fmaxf(0.0f, iy);
  float inter = ix * iy;
  float denom = ((aa + ba) - inter) + 1e-6f;
  float t = 0.7f * denom;
  mm = fminf(mm, fabsf(inter - t) - 2e-5f * t);   // band >> max rounding skew (~4e-7)
  return inter > t;
}
__device__ __forceinline__ bool iou_exact(float4 a, float aa, float4 b, float ba) {
  float ix = fminf(a.z, b.z) - fmaxf(a.x, b.x); ix = fmaxf(0.0f, ix);
  float iy = fminf(a.w, b.w) - fmaxf(a.y, b.y); iy = fmaxf(0.0f, iy);
  float inter = ix * iy;
  float denom = ((aa + ba) - inter) + 1e-6f;
  return (inter / denom) > NMS_TH;
}
__device__ __forceinline__ int bin_coord(float c) {
  int v = (int)(c * 0.25f);                        // trunc==clamp-consistent for <0
  return v < 0 ? 0 : (v > BGRID - 1 ? BGRID - 1 : v);
}

// score/label/key for 4 points per thread (vectorized). Per-block PARTIAL
// histogram with plain stores — no global atomics, no pre-zero, no fence.
__global__ __launch_bounds__(256) void score_hist_kernel(const float* __restrict__ cls,
                                                         int* __restrict__ labels,
                                                         u64* __restrict__ keys,
                                                         u32* __restrict__ histP) {
  __shared__ u32 lh[2048];
  for (int t = threadIdx.x; t < 2048; t += 256) lh[t] = 0;
  __syncthreads();
  int t4 = blockIdx.x * 256 + threadIdx.x;
  int base4 = t4 * 4;                               // first point id (batches 4-aligned)
  const float4* c4 = (const float4*)(cls + (size_t)t4 * 12);
  float4 va = c4[0], vb = c4[1], vc = c4[2];
  float v[12] = {va.x, va.y, va.z, va.w, vb.x, vb.y, vb.z, vb.w, vc.x, vc.y, vc.z, vc.w};
  u64 ks[4]; int ls[4];
#pragma unroll
  for (int p = 0; p < 4; ++p) {
    float s = v[3 * p]; int l = 0;
    if (v[3 * p + 1] > s) { s = v[3 * p + 1]; l = 1; }
    if (v[3 * p + 2] > s) { s = v[3 * p + 2]; l = 2; }
    int n = (base4 + p) & (NN - 1);
    ks[p] = ((u64)orderable(s) << 32) | (u32)(~(u32)n);
    ls[p] = l;
    atomicAdd(&lh[bucket_of(s)], 1u);
  }
  *(ulonglong2*)(keys + base4) = make_ulonglong2(ks[0], ks[1]);
  *(ulonglong2*)(keys + base4 + 2) = make_ulonglong2(ks[2], ks[3]);
  *(int4*)(labels + base4) = make_int4(ls[0], ls[1], ls[2], ls[3]);
  __syncthreads();
  u32* myrow = histP + (size_t)blockIdx.x * 2048;
  for (int t = threadIdx.x; t < 2048; t += 256) myrow[t] = lh[t];
}

// Per batch: sum the 32 partial histograms, suffix-scan, find threshold bucket
// T, init per-bucket cursors. Zeroes this batch's mid counter and maxW.
__global__ __launch_bounds__(256) void select_kernel(const u32* __restrict__ histP,
                                                     u32* __restrict__ selinfo,
                                                     u32* __restrict__ sfxBuf,
                                                     u32* __restrict__ cursor,
                                                     u32* __restrict__ cnt_mid,
                                                     u32* __restrict__ maxWG) {
  __shared__ u32 sfx[2048];
  int b = blockIdx.x;
  if (threadIdx.x == 0) { cnt_mid[b] = 0; maxWG[b] = 0; }
  for (int t = threadIdx.x; t < 2048; t += 256) {
    u32 s = 0;
    const u32* pp = histP + (size_t)(b * 32) * 2048 + t;
#pragma unroll
    for (int j = 0; j < 32; ++j) s += pp[(size_t)j * 2048];
    sfx[t] = s;
  }
  __syncthreads();
  for (int d = 1; d < 2048; d <<= 1) {
    u32 v[8];
#pragma unroll
    for (int i = 0; i < 8; ++i) {
      int t = threadIdx.x + i * 256;
      v[i] = (t + d < 2048) ? sfx[t + d] : 0;
    }
    __syncthreads();
#pragma unroll
    for (int i = 0; i < 8; ++i) sfx[threadIdx.x + i * 256] += v[i];
    __syncthreads();
  }
  for (int t = threadIdx.x; t < 2048; t += 256) {
    u32 above = (t + 1 < 2048) ? sfx[t + 1] : 0;
    sfxBuf[b * 2048 + t] = sfx[t];
    cursor[b * 2048 + t] = above;                       // segment base
    if (above < PRE && sfx[t] >= PRE) { selinfo[b * 2] = (u32)t; selinfo[b * 2 + 1] = above; }
  }
}

// Compact, 4 keys/thread (2x ulonglong2 loads): hi keys scatter into their
// bucket's segment via per-bucket cursors; mid keys to the tie-break buffer.
__global__ __launch_bounds__(256) void compact_kernel(const u64* __restrict__ keys,
                                                      const u32* __restrict__ selinfo,
                                                      u32* __restrict__ cursor,
                                                      u64* __restrict__ sel, u64* __restrict__ mid,
                                                      u32* __restrict__ cnt_mid) {
  int t4 = blockIdx.x * 256 + threadIdx.x;
  int base4 = t4 * 4;
  int b = base4 >> 15;
  u32 T = selinfo[b * 2];
  ulonglong2 k01 = *(const ulonglong2*)(keys + base4);
  ulonglong2 k23 = *(const ulonglong2*)(keys + base4 + 2);
  u64 kk[4] = {k01.x, k01.y, k23.x, k23.y};
#pragma unroll
  for (int p = 0; p < 4; ++p) {
    u64 key = kk[p];
    u32 bk = bucket_of(unorderable((u32)(key >> 32)));
    if (bk > T) {
      u32 q = atomicAdd(&cursor[b * 2048 + bk], 1u);
      sel[((size_t)b << 12) + q] = key;
    } else if (bk == T) {
      u32 q = atomicAdd(&cnt_mid[b], 1u);
      if (q < MIDCAP) mid[(size_t)b * MIDCAP + q] = key;   // ~45 expected with this data
    }
  }
}

// One wave per (batch, bucket). Buckets > T: in-register 64-lane bitonic sort.
// Bucket == T: fused midsel. Then fused gather of P/AR/topS; tracks the max
// box extent (atomicMax) for the NMS spatial-hash reach.
__global__ __launch_bounds__(64) void bsort_kernel(u64* __restrict__ sel, u64* __restrict__ mid,
                                                   const u32* __restrict__ sfxBuf,
                                                   const u32* __restrict__ selinfo,
                                                   const u32* __restrict__ cnt_mid,
                                                   const float* __restrict__ boxes,
                                                   float4* __restrict__ P,
                                                   float* __restrict__ AR,
                                                   float* __restrict__ topS,
                                                   u32* __restrict__ maxWG) {
  int t = blockIdx.x & 2047;
  int b = blockIdx.x >> 11;
  int lane = threadIdx.x;
  u32 T = selinfo[b * 2];
  if ((u32)t < T) return;
  u64* selB = sel + ((size_t)b << 12);
  u32 start, end;
  if ((u32)t == T) {
    u32 C1 = selinfo[b * 2 + 1];
    int need = PRE - (int)C1;
    int M = (int)cnt_mid[b]; if (M > MIDCAP) M = MIDCAP;
    u64* midB = mid + (size_t)b * MIDCAP;
    for (int r = 0; r < need; ++r) {
      u64 best = 0; int bi = -1;
      for (int q = lane; q < M; q += 64) {
        u64 v = midB[q];
        if (v > best) { best = v; bi = q; }
      }
#pragma unroll
      for (int d = 32; d > 0; d >>= 1) {
        u64 ob = __shfl_xor(best, d, 64);
        int oi = __shfl_xor(bi, d, 64);
        if (ob > best) { best = ob; bi = oi; }
      }
      if (lane == 0) selB[C1 + r] = best;
      if (bi >= 0 && lane == (bi & 63)) midB[bi] = 0;    // remove chosen
    }
    start = C1; end = PRE;
  } else {
    start = (t < 2047) ? sfxBuf[b * 2048 + t + 1] : 0u;
    end = sfxBuf[b * 2048 + t];
    int n = (int)(end - start);
    if (n > 64) {
      // robustness fallback (never hit on bench data): selection sort
      for (int r = 0; r < n - 1; ++r) {
        u64 best = 0; int bi = -1;
        for (int q = r + lane; q < n; q += 64) {
          u64 v = selB[start + q];
          if (v > best) { best = v; bi = q; }
        }
#pragma unroll
        for (int d = 32; d > 0; d >>= 1) {
          u64 ob = __shfl_xor(best, d, 64);
          int oi = __shfl_xor(bi, d, 64);
          if (ob > best) { best = ob; bi = oi; }
        }
        if (lane == 0) {
          u64 tmp = selB[start + r];
          selB[start + r] = best;
          selB[start + bi] = tmp;
        }
      }
    } else if (n > 1) {
      u64 v = (lane < n) ? selB[start + lane] : 0ULL;    // MSB-set keys: pad sinks
#pragma unroll
      for (int k = 2; k <= 64; k <<= 1) {
#pragma unroll
        for (int j = k >> 1; j > 0; j >>= 1) {
          u64 o = __shfl_xor(v, j, 64);
          bool up = ((lane & k) == 0);
          bool first = ((lane & j) == 0);
          u64 mx = v > o ? v : o, mn = v > o ? o : v;
          v = (first == up) ? mx : mn;
        }
      }
      if (lane < n) selB[start + lane] = v;
    }
  }
  __builtin_amdgcn_s_waitcnt(0);                         // selB writes visible to this wave
  // ---- fused gather (P/AR/topS) + max-extent tracking for [start, end) ----
  float wmax = 0.0f;
  for (u32 pos = start + lane; pos < end; pos += 64) {
    u64 key = selB[pos];
    u32 n = ~(u32)key;
    const float* bx = boxes + ((size_t)b * NN + n) * 7;
    float x = bx[0], y = bx[1], dx = bx[3], dy = bx[4];
    size_t gidx = ((size_t)b << 12) + pos;
    float4 p;
    p.x = x - 0.5f * dx; p.z = x + 0.5f * dx;   // 0.5*dx exact -> contraction-safe
    p.y = y - 0.5f * dy; p.w = y + 0.5f * dy;
    P[gidx] = p;
    AR[gidx] = dx * dy;
    topS[gidx] = unorderable((u32)(key >> 32));
    wmax = fmaxf(wmax, fmaxf(dx, dy));
  }
#pragma unroll
  for (int d = 32; d > 0; d >>= 1) wmax = fmaxf(wmax, __shfl_xor(wmax, d, 64));
  if (lane == 0 && wmax > 0.0f)
    atomicMax(&maxWG[b], __float_as_uint(wmax));         // positive-float bits: monotone
}

// Greedy NMS vs LDS kept list accelerated by an 18x18 spatial hash: a kept box
// can only suppress candidates within maxW of its center, so each candidate
// checks ~(2r+1)^2 bins (~15 IoUs) instead of the whole kept list (~500).
// Skipped pairs provably have inter==0 -> IoU=0<0.7, never marginal -> exact.
// Bin overflow (>BCAP) sets a flag -> full-scan fallback (R21-verified path).
__global__ __launch_bounds__(1024, 1) void nms_final_kernel(
    const float4* __restrict__ Pg, const float* __restrict__ ARg,
    const float* __restrict__ topS, const u64* __restrict__ selG,
    const float* __restrict__ boxes, const int* __restrict__ labels,
    const u32* __restrict__ maxWG, float* __restrict__ out) {
  __shared__ float4 ldsP[LROWS];
  __shared__ float ldsAR[LROWS];
  __shared__ float4 keptP[KCAP];
  __shared__ float keptAR[KCAP];
  __shared__ u16 binList[BINS * BCAP];
  __shared__ u32 binCnt[BINS];
  __shared__ u64 dLDS[64];
  __shared__ u64 kwLDS[64];
  __shared__ u32 supArr[64];
  __shared__ int keptIdx[POST];
  __shared__ u32 knSh, finSh, ovflSh;
  int b = blockIdx.x;
  int tid = threadIdx.x;
  int wv = tid >> 6, lane = tid & 63;
  size_t pb = (size_t)b << 12;
  // stage first 1024 rows to LDS (one coalesced round); init hash + state
  ldsP[tid] = Pg[pb + tid];
  ldsAR[tid] = ARg[pb + tid];
  if (tid < BINS) binCnt[tid] = 0;
  if (tid == 0) { knSh = 0; ovflSh = 0; }
  if (tid < 64) kwLDS[tid] = 0;
  __syncthreads();
  float maxW = __uint_as_float(maxWG[b]);
  int rch = 1 + (int)(maxW * 0.25f);               // >= ceil(maxW/4)
  if (rch > BGRID - 1) rch = BGRID - 1;
  for (int g = 0; g < 64; ++g) {
    int kn0 = (int)knSh;                           // stable since last barrier
    bool ovf = (ovflSh != 0);
    // 1. sup pass: wave wv owns candidates 4wv..4wv+3; 16 lanes split the work
    int cj = g * 64 + 4 * wv + (lane >> 4);
    float4 cp; float car;
    if (cj < LROWS) { cp = ldsP[cj]; car = ldsAR[cj]; }
    else { cp = Pg[pb + cj]; car = ARg[pb + cj]; }
    int cbx = bin_coord((cp.x + cp.z) * 0.5f);
    int cby = bin_coord((cp.y + cp.w) * 0.5f);
    int x0 = cbx - rch < 0 ? 0 : cbx - rch, x1 = cbx + rch > BGRID - 1 ? BGRID - 1 : cbx + rch;
    int y0 = cby - rch < 0 ? 0 : cby - rch, y1 = cby + rch > BGRID - 1 ? BGRID - 1 : cby + rch;
    bool hit = false; float mm = 1.0f;
    if (kn0 > 0) {
      if (!ovf) {
        for (int yy = y0; yy <= y1; ++yy)
          for (int xx = x0; xx <= x1; ++xx) {
            int bi = yy * BGRID + xx;
            int cnt = (int)binCnt[bi];
            for (int e = lane & 15; e < cnt; e += 16) {
              int m = binList[bi * BCAP + e];
              hit |= iou_fast(keptP[m], keptAR[m], cp, car, mm);
            }
          }
      } else {
        int m = lane & 15;
        for (; m + 48 < kn0; m += 64) {            // x4 unroll: 4 loads in flight
          hit |= iou_fast(keptP[m], keptAR[m], cp, car, mm);
          hit |= iou_fast(keptP[m + 16], keptAR[m + 16], cp, car, mm);
          hit |= iou_fast(keptP[m + 32], keptAR[m + 32], cp, car, mm);
          hit |= iou_fast(keptP[m + 48], keptAR[m + 48], cp, car, mm);
        }
        for (; m < kn0; m += 16)
          hit |= iou_fast(keptP[m], keptAR[m], cp, car, mm);
      }
      if (__any(mm <= 0.0f)) {                     // rare: exact-divide redo
        hit = false;
        if (!ovf) {
          for (int yy = y0; yy <= y1; ++yy)
            for (int xx = x0; xx <= x1; ++xx) {
              int bi = yy * BGRID + xx;
              int cnt = (int)binCnt[bi];
              for (int e = lane & 15; e < cnt; e += 16) {
                int m = binList[bi * BCAP + e];
                hit |= iou_exact(keptP[m], keptAR[m], cp, car);
              }
            }
        } else {
          for (int m2 = lane & 15; m2 < kn0; m2 += 16)
            hit |= iou_exact(keptP[m2], keptAR[m2], cp, car);
        }
      }
    }
    u64 bal = __ballot(hit);
    int q = lane >> 4;
    if ((lane & 15) == 0)
      supArr[4 * wv + q] = (((bal >> (16 * q)) & 0xFFFFull) != 0ull) ? 1u : 0u;
    // 2. intra-group tile: wave wv computes rows 4wv..4wv+3 (lane = column)
    int colj = g * 64 + lane;
    float4 cq; float cqa;
    if (colj < LROWS) { cq = ldsP[colj]; cqa = ldsAR[colj]; }
    else { cq = Pg[pb + colj]; cqa = ARg[pb + colj]; }
#pragma unroll
    for (int rr = 0; rr < 4; ++rr) {
      int rj = g * 64 + 4 * wv + rr;
      float4 rp; float rar;
      if (rj < LROWS) { rp = ldsP[rj]; rar = ldsAR[rj]; }
      else { rp = Pg[pb + rj]; rar = ARg[pb + rj]; }
      float mm2 = 1.0f;
      bool sup = iou_fast(rp, rar, cq, cqa, mm2);
      if (__any(mm2 <= 0.0f)) sup = iou_exact(rp, rar, cq, cqa);
      u64 dw = __ballot(sup);
      if (lane == 0) dLDS[4 * wv + rr] = dw;
    }
    __syncthreads();
    // 3. wave 0: sparse intra-group recurrence + append kept to LDS + hash
    if (wv == 0) {
      u64 d_cur = dLDS[lane];
      u64 sup_word = __ballot(supArr[lane] != 0u);
      u64 aboveMask = ~((2ULL << lane) - 1ULL);    // lane=63 -> 0
      u64 rem = __ballot((d_cur & aboveMask) != 0ULL);
      if (rem) {                                   // rare: real intra suppressors
        do {
          int k = __ffsll((long long)rem) - 1;
          rem &= rem - 1;
          if (!((sup_word >> k) & 1ULL))           // row k kept -> apply bits >k
            sup_word |= readlane64(d_cur, k) & ~((2ULL << k) - 1ULL);
        } while (rem);
      }
      u64 keep = ~sup_word;
      int cnt = __popcll(keep);
      int rank = (int)__popcll(keep & ((1ULL << lane) - 1ULL));
      if ((keep >> lane) & 1ULL) {                 // kn0+rank <= 574 < KCAP
        int bi = g * 64 + lane;
        float4 kp; float ka;
        if (bi < LROWS) { kp = ldsP[bi]; ka = ldsAR[bi]; }
        else { kp = Pg[pb + bi]; ka = ARg[pb + bi]; }
        int kpos = kn0 + rank;
        keptP[kpos] = kp;
        keptAR[kpos] = ka;
        int hb = bin_coord((kp.y + kp.w) * 0.5f) * BGRID + bin_coord((kp.x + kp.z) * 0.5f);
        u32 slot = atomicAdd(&binCnt[hb], 1u);
        if (slot < BCAP) binList[hb * BCAP + slot] = (u16)kpos;
        else { ovflSh = 1; binCnt[hb] = BCAP; }    // clamp; fallback takes over
      }
      if (lane == 0) { kwLDS[g] = keep; knSh = (u32)(kn0 + cnt); }
    }
    __syncthreads();
    if (knSh >= POST) break;                       // uniform
  }
  // ---- finalize stage 1 (wave 0): expand keep words into LDS keptIdx ----
  if (wv == 0) {
    u64 kw = kwLDS[lane];
    int cnt = __popcll(kw);
    int pfx = cnt;
#pragma unroll
    for (int d = 1; d < 64; d <<= 1) {
      int up = __shfl_up(pfx, d, 64);
      if (lane >= d) pfx += up;
    }
    int total = __shfl(pfx, 63, 64);
    int pos = pfx - cnt;
    while (kw) {
      int t = __ffsll((long long)kw) - 1;
      kw &= kw - 1;
      if (pos < POST) keptIdx[pos] = (lane << 6) + t;
      ++pos;
    }
    if (lane == 0) finSh = (u32)(total < POST ? total : POST);
  }
  __syncthreads();
  // ---- finalize stage 2 (all 1024 threads): write the 512 output slots ----
  int fin = (int)finSh;
  float* outR = out;
  float* outS = out + BB * POST * 7;
  float* outL = outS + BB * POST;
  for (int s = tid; s < POST; s += 1024) {
    int gdx = (b << 9) + s;
    if (s < fin) {
      int i = keptIdx[s];
      u64 key = selG[pb + i];
      u32 n = ~(u32)key;
      size_t src = (size_t)b * NN + n;
      const float* bx = boxes + src * 7;
#pragma unroll
      for (int c = 0; c < 7; ++c) outR[(size_t)gdx * 7 + c] = bx[c];
      outS[gdx] = topS[pb + i];
      outL[gdx] = (float)(labels[src] + 1);
    } else {                                       // empty slots: 0 / 0 / label 1
#pragma unroll
      for (int c = 0; c < 7; ++c) outR[(size_t)gdx * 7 + c] = 0.0f;
      outS[gdx] = 0.0f;
      outL[gdx] = 1.0f;
    }
  }
}

extern "C" void kernel_launch(void* const* d_in, const int* in_sizes, int n_in,
                              void* d_out, int out_size, void* d_ws, size_t ws_size,
                              hipStream_t stream) {
  const float* boxes = (const float*)d_in[0];   // (4,32768,7)
  const float* cls   = (const float*)d_in[1];   // (4,32768,3)
  float* out = (float*)d_out;

  // ---- workspace carve-up (~2.5 MB) ----
  char* p = (char*)d_ws;
  auto take = [&](size_t bytes) { char* r = p; p += (bytes + 255) & ~(size_t)255; return (void*)r; };
  u64*   keys    = (u64*)  take((size_t)BB * NN * 8);
  int*   labels  = (int*)  take((size_t)BB * NN * 4);
  u32*   histP   = (u32*)  take((size_t)BB * 32 * 2048 * 4);   // per-block partials
  u32*   selinfo = (u32*)  take((size_t)BB * 2 * 4);
  u32*   sfxBuf  = (u32*)  take((size_t)BB * 2048 * 4);
  u32*   cursor  = (u32*)  take((size_t)BB * 2048 * 4);
  u32*   cnt_mid = (u32*)  take((size_t)BB * 4);
  u32*   maxWG   = (u32*)  take((size_t)BB * 4);
  u64*   sel     = (u64*)  take((size_t)BB * PRE * 8);
  u64*   mid     = (u64*)  take((size_t)BB * MIDCAP * 8);
  float4* Pg     = (float4*)take((size_t)BB * PRE * 16);
  float* ARg     = (float*)take((size_t)BB * PRE * 4);
  float* topS    = (float*)take((size_t)BB * PRE * 4);

  score_hist_kernel<<<BB * NN / 1024, 256, 0, stream>>>(cls, labels, keys, histP);
  select_kernel<<<BB, 256, 0, stream>>>(histP, selinfo, sfxBuf, cursor, cnt_mid, maxWG);
  compact_kernel<<<BB * NN / 1024, 256, 0, stream>>>(keys, selinfo, cursor, sel, mid, cnt_mid);
  bsort_kernel<<<BB * 2048, 64, 0, stream>>>(sel, mid, sfxBuf, selinfo, cnt_mid,
                                             boxes, Pg, ARg, topS, maxWG);
  nms_final_kernel<<<BB, 1024, 0, stream>>>(Pg, ARg, topS, sel, boxes, labels, maxWG, out);
}